// Round 2
// baseline (1072.398 us; speedup 1.0000x reference)
//
#include <hip/hip_runtime.h>
#include <stddef.h>
#include <stdint.h>

#define N_NODES 50000
#define N_EDGES 800000
#define NF 96
#define FE 64
#define DIN 256
#define DOUT 192
#define BN_EPS 1e-5f
#define NTILES (N_EDGES / 64)

typedef float f32x4 __attribute__((ext_vector_type(4)));
typedef short bf16x8 __attribute__((ext_vector_type(8)));

__device__ __forceinline__ unsigned short f2bf(float f) {
  unsigned int u = __float_as_uint(f);
  return (unsigned short)((u + 0x7fffu + ((u >> 16) & 1u)) >> 16);
}
__device__ __forceinline__ float sigmoidf_(float x) { return 1.f / (1.f + __expf(-x)); }
__device__ __forceinline__ float softplusf_(float x) {
  return fmaxf(x, 0.f) + log1pf(__expf(-fabsf(x)));
}
__device__ __forceinline__ void gload_lds16(const void* g, void* l) {
  __builtin_amdgcn_global_load_lds(
      (const __attribute__((address_space(1))) void*)g,
      (__attribute__((address_space(3))) void*)l, 16, 0, 0);
}

// column permutation: our col c' = t*16+lm -> orig col
// lm<8: gate col t*8+lm ; lm>=8: conv col 96 + t*8 + (lm-8)
__device__ __forceinline__ int col_perm(int c) {
  int t = c >> 4, lm = c & 15;
  return (lm < 8) ? (t * 8 + lm) : (96 + t * 8 + lm - 8);
}

// ---------------- conversion kernels ----------------
__global__ void k_cvt(const float* __restrict__ in, unsigned short* __restrict__ out, int n4) {
  int stride = gridDim.x * blockDim.x;
  for (int i = blockIdx.x * blockDim.x + threadIdx.x; i < n4; i += stride) {
    float4 v = reinterpret_cast<const float4*>(in)[i];
    ushort4 o;
    o.x = f2bf(v.x); o.y = f2bf(v.y); o.z = f2bf(v.z); o.w = f2bf(v.w);
    reinterpret_cast<ushort4*>(out)[i] = o;
  }
}

// Wt[c'][k] = bf16(W[k][perm(c')])  (192 x 256, K-contiguous, permuted cols)
__global__ void k_cvt_w(const float* __restrict__ W, unsigned short* __restrict__ Wt) {
  int i = blockIdx.x * blockDim.x + threadIdx.x;
  if (i < DOUT * DIN) {
    int c = i / DIN, k = i % DIN;
    Wt[i] = f2bf(W[k * DOUT + col_perm(c)]);
  }
}

__global__ void k_hist(const int* __restrict__ idx1, float* __restrict__ counts) {
  int stride = gridDim.x * blockDim.x;
  for (int e = blockIdx.x * blockDim.x + threadIdx.x; e < N_EDGES; e += stride)
    atomicAdd(&counts[idx1[e]], 1.0f);
}

// ---------------- fused gather + GEMM, W in registers ----------------
// block = 4 waves; wave w owns our-cols [w*48, w*48+48) (3 MFMA col-tiles),
// all 64 rows of the A tile. B fragments live in registers (loaded once).
// A tile 64x256 bf16 staged in LDS via global_load_lds, src-side XOR swizzle.
// PASS 0: per-col sum/sumsq of y = XW (bias folded later)
// PASS 1: zhat = y*a1 + b1f ; msg = sigmoid(gate)*softplus(conv) via shfl_xor(8);
//         atomic scatter-add into sums[idx1[e]*96 + g]
template <int PASS>
__global__ __launch_bounds__(256, 2) void k_gemm(
    const unsigned short* __restrict__ nb, const unsigned short* __restrict__ eb,
    const unsigned short* __restrict__ Wt, const int* __restrict__ idx1,
    const int* __restrict__ idx2, const float* __restrict__ cvec0,
    const float* __restrict__ cvec1, float* __restrict__ out1, float* __restrict__ out2) {
  __shared__ unsigned short As[64 * 256];  // 32 KB

  const int tid = threadIdx.x;
  const int lane = tid & 63;
  const int w = tid >> 6;
  const int lm = lane & 15;
  const int hi = lane >> 4;
  const int base_c = w * 48;

  // ---- load B fragments for this wave's 48 cols, all K=256 ----
  bf16x8 breg[3][8];
#pragma unroll
  for (int ct = 0; ct < 3; ++ct)
#pragma unroll
    for (int ks = 0; ks < 8; ++ks)
      breg[ct][ks] = *reinterpret_cast<const bf16x8*>(
          Wt + (size_t)(base_c + ct * 16 + lm) * DIN + ks * 32 + hi * 8);

  float c0[3], c1[3];
  float s1a[3] = {0.f, 0.f, 0.f}, s2a[3] = {0.f, 0.f, 0.f};
  if (PASS == 1) {
#pragma unroll
    for (int ct = 0; ct < 3; ++ct) {
      c0[ct] = cvec0[base_c + ct * 16 + lm];
      c1[ct] = cvec1[base_c + ct * 16 + lm];
    }
  }

  for (int tile = blockIdx.x; tile < NTILES; tile += gridDim.x) {
    const int e0 = tile * 64;

    __syncthreads();  // previous tile's LDS readers done
    // ---- stage A: 64 rows x 256 k; wave w stages rows [w*16, w*16+16) ----
    // LDS linear; global src pre-swizzled: slot cs holds chunk cs^(r&7)
#pragma unroll
    for (int s = 0; s < 8; ++s) {
      int rbase = (w << 4) + (s << 1);
      int r = rbase + (lane >> 5);
      int cs = lane & 31;
      int g = cs ^ (r & 7);
      int e = e0 + r;
      const unsigned short* src;
      if (g < 12)      src = nb + (size_t)idx1[e] * NF + g * 8;
      else if (g < 24) src = nb + (size_t)idx2[e] * NF + (g - 12) * 8;
      else             src = eb + (size_t)e * FE + (g - 24) * 8;
      gload_lds16(src, &As[rbase * 256]);
    }
    __syncthreads();

    // ---- compute: 8 K-steps, 4 row-frags x 3 col-tiles ----
    f32x4 acc[4][3];
#pragma unroll
    for (int rf = 0; rf < 4; ++rf)
#pragma unroll
      for (int ct = 0; ct < 3; ++ct) acc[rf][ct] = (f32x4)(0.f);

#pragma unroll
    for (int ks = 0; ks < 8; ++ks) {
      bf16x8 a[4];
#pragma unroll
      for (int rf = 0; rf < 4; ++rf) {
        int r = rf * 16 + lm;
        int slot = (ks * 4 + hi) ^ (r & 7);
        a[rf] = *reinterpret_cast<const bf16x8*>(&As[r * 256 + slot * 8]);
      }
#pragma unroll
      for (int rf = 0; rf < 4; ++rf)
#pragma unroll
        for (int ct = 0; ct < 3; ++ct)
          acc[rf][ct] =
              __builtin_amdgcn_mfma_f32_16x16x32_bf16(a[rf], breg[ct][ks], acc[rf][ct], 0, 0, 0);
    }

    // ---- epilogue ----
    if (PASS == 0) {
#pragma unroll
      for (int ct = 0; ct < 3; ++ct)
#pragma unroll
        for (int rf = 0; rf < 4; ++rf)
#pragma unroll
          for (int j = 0; j < 4; ++j) {
            float y = acc[rf][ct][j];
            s1a[ct] += y;
            s2a[ct] += y * y;
          }
    } else {
#pragma unroll
      for (int rf = 0; rf < 4; ++rf)
#pragma unroll
        for (int j = 0; j < 4; ++j) {
          int e = e0 + rf * 16 + hi * 4 + j;
          int dst = idx1[e] * NF;
#pragma unroll
          for (int ct = 0; ct < 3; ++ct) {
            float z = acc[rf][ct][j] * c0[ct] + c1[ct];
            float v = (lm < 8) ? sigmoidf_(z) : softplusf_(z);
            float p = __shfl_xor(v, 8);
            if (lm < 8) {
              int g = (w * 3 + ct) * 8 + lm;  // orig gate/msg col
              atomicAdd(&out1[dst + g], v * p);
            }
          }
        }
    }
  }

  if (PASS == 0) {
    // reduce col stats across the 4 hi-groups, then one atomic per col
#pragma unroll
    for (int ct = 0; ct < 3; ++ct) {
      float s1 = s1a[ct], s2 = s2a[ct];
      s1 += __shfl_xor(s1, 16); s2 += __shfl_xor(s2, 16);
      s1 += __shfl_xor(s1, 32); s2 += __shfl_xor(s2, 32);
      if (lane < 16) {
        atomicAdd(&out1[base_c + ct * 16 + lane], s1);
        atomicAdd(&out2[base_c + ct * 16 + lane], s2);
      }
    }
  }
}

// ---------------- BN affine computation ----------------
// colsum/colsumsq are stats of y = XW (no bias) in OUR col space.
// z = y + b[orig]; mean_z = mean_y + b, var_z = var_y.
// zhat = y*a1 + b1f with a1 = gamma/sqrt(var+eps), b1f = beta - mean_y*a1... 
// full: zhat = (z-mean_z)*a + beta = y*a + beta - mean_y*a
__global__ void k_bn1(const float* __restrict__ colsum, const float* __restrict__ colsumsq,
                      const float* __restrict__ b, const float* __restrict__ gamma1,
                      const float* __restrict__ beta1, float* __restrict__ a1,
                      float* __restrict__ b1f) {
  int c = threadIdx.x;  // 192, our col space
  int o = col_perm(c);
  float my = colsum[c] * (1.f / N_EDGES);
  float v = colsumsq[c] * (1.f / N_EDGES) - my * my;
  float a = gamma1[o] * rsqrtf(v + BN_EPS);
  a1[c] = a;
  b1f[c] = beta1[o] - my * a;
  (void)b;  // bias cancels: (y + b - (my + b)) = y - my
}

__global__ void k_nodestats(const float* __restrict__ sums, const float* __restrict__ counts,
                            float* __restrict__ colsum2, float* __restrict__ colsumsq2) {
  __shared__ float sh[2][2][96];
  int t = threadIdx.x;  // 192
  int c = t % 96, sub = t / 96;
  float s1 = 0.f, s2 = 0.f;
  int n0 = blockIdx.x * 256;
  for (int r = sub; r < 256; r += 2) {
    int n = n0 + r;
    if (n < N_NODES) {
      float v = sums[(size_t)n * NF + c] / fmaxf(counts[n], 1.f);
      s1 += v; s2 += v * v;
    }
  }
  sh[0][sub][c] = s1; sh[1][sub][c] = s2;
  __syncthreads();
  if (sub == 0) {
    atomicAdd(&colsum2[c], s1 + sh[0][1][c]);
    atomicAdd(&colsumsq2[c], s2 + sh[1][1][c]);
  }
}

__global__ void k_bn2(const float* __restrict__ colsum2, const float* __restrict__ colsumsq2,
                      const float* __restrict__ gamma2, const float* __restrict__ beta2,
                      float* __restrict__ a2, float* __restrict__ b2f) {
  int c = threadIdx.x;
  if (c < 96) {
    float m = colsum2[c] * (1.f / N_NODES);
    float v = colsumsq2[c] * (1.f / N_NODES) - m * m;
    float a = gamma2[c] * rsqrtf(v + BN_EPS);
    a2[c] = a;
    b2f[c] = beta2[c] - m * a;
  }
}

__global__ void k_final(const float* __restrict__ node, const float* __restrict__ sums,
                        const float* __restrict__ counts, const float* __restrict__ a2,
                        const float* __restrict__ b2f, float* __restrict__ out) {
  int stride = gridDim.x * blockDim.x;
  for (int i = blockIdx.x * blockDim.x + threadIdx.x; i < N_NODES * NF / 4; i += stride) {
    int n = i / 24, c4 = (i % 24) * 4;
    float inv = 1.f / fmaxf(counts[n], 1.f);
    float4 s = reinterpret_cast<const float4*>(sums)[i];
    float4 nf = reinterpret_cast<const float4*>(node)[i];
    float4 o;
    o.x = softplusf_(nf.x + s.x * inv * a2[c4 + 0] + b2f[c4 + 0]);
    o.y = softplusf_(nf.y + s.y * inv * a2[c4 + 1] + b2f[c4 + 1]);
    o.z = softplusf_(nf.z + s.z * inv * a2[c4 + 2] + b2f[c4 + 2]);
    o.w = softplusf_(nf.w + s.w * inv * a2[c4 + 3] + b2f[c4 + 3]);
    reinterpret_cast<float4*>(out)[i] = o;
  }
}

extern "C" void kernel_launch(void* const* d_in, const int* in_sizes, int n_in,
                              void* d_out, int out_size, void* d_ws, size_t ws_size,
                              hipStream_t stream) {
  const float* node = (const float*)d_in[0];
  const float* edge = (const float*)d_in[1];
  const float* W = (const float*)d_in[2];
  const float* b = (const float*)d_in[3];
  const float* gamma1 = (const float*)d_in[4];
  const float* beta1 = (const float*)d_in[5];
  const float* gamma2 = (const float*)d_in[6];
  const float* beta2 = (const float*)d_in[7];
  const int* idx1 = (const int*)d_in[8];
  const int* idx2 = (const int*)d_in[9];
  float* out = (float*)d_out;

  char* ws = (char*)d_ws;
  unsigned short* nb = (unsigned short*)(ws);                    //  9,600,000
  unsigned short* eb = (unsigned short*)(ws + 9600000);          // 102,400,000
  unsigned short* Wt = (unsigned short*)(ws + 112000000);        //      98,304
  float* sums  = (float*)(ws + 112098304);                       //  19,200,000
  float* counts = (float*)(ws + 131298304);                      //     200,000
  float* stats = (float*)(ws + 131498304);
  float* colsum1 = stats;          // 192
  float* colsumsq1 = stats + 192;  // 192
  float* colsum2 = stats + 384;    // 96
  float* colsumsq2 = stats + 480;  // 96
  float* a1 = stats + 576;         // 192
  float* b1f = stats + 768;        // 192
  float* a2 = stats + 960;         // 96
  float* b2f = stats + 1056;       // 96

  hipMemsetAsync(ws + 112098304, 0, 19200000 + 200000 + 4608, stream);

  k_cvt<<<2048, 256, 0, stream>>>(node, nb, N_NODES * NF / 4);
  k_cvt<<<2048, 256, 0, stream>>>(edge, eb, N_EDGES * FE / 4);
  k_cvt_w<<<DOUT * DIN / 256, 256, 0, stream>>>(W, Wt);
  k_hist<<<1024, 256, 0, stream>>>(idx1, counts);

  k_gemm<0><<<2048, 256, 0, stream>>>(nb, eb, Wt, idx1, idx2, nullptr, nullptr,
                                      colsum1, colsumsq1);
  k_bn1<<<1, 192, 0, stream>>>(colsum1, colsumsq1, b, gamma1, beta1, a1, b1f);
  k_gemm<1><<<2048, 256, 0, stream>>>(nb, eb, Wt, idx1, idx2, a1, b1f, sums, nullptr);

  k_nodestats<<<(N_NODES + 255) / 256, 192, 0, stream>>>(sums, counts, colsum2, colsumsq2);
  k_bn2<<<1, 128, 0, stream>>>(colsum2, colsumsq2, gamma2, beta2, a2, b2f);
  k_final<<<2048, 256, 0, stream>>>(node, sums, counts, a2, b2f, out);
}